// Round 10
// baseline (365.326 us; speedup 1.0000x reference)
//
#include <hip/hip_runtime.h>

#define CLAMP_THR 0.9999999f

// 4-byte-aligned float4 (element base 9*e is only dword-aligned)
typedef float f4a __attribute__((ext_vector_type(4), aligned(4)));

__global__ void zero_loss_kernel(float* out) {
    if (threadIdx.x == 0) out[0] = 0.0f;
}

__device__ __forceinline__ void load27(const float* __restrict__ Rrel,
                                       const float* __restrict__ Rw2,
                                       const float* __restrict__ Rw1,
                                       size_t b,
                                       float R[9], float A[9], float B[9])
{
    f4a v;
    v = *(const f4a*)(Rrel + b);     R[0]=v.x; R[1]=v.y; R[2]=v.z; R[3]=v.w;
    v = *(const f4a*)(Rrel + b + 4); R[4]=v.x; R[5]=v.y; R[6]=v.z; R[7]=v.w;
    R[8] = Rrel[b + 8];
    v = *(const f4a*)(Rw2 + b);      A[0]=v.x; A[1]=v.y; A[2]=v.z; A[3]=v.w;
    v = *(const f4a*)(Rw2 + b + 4);  A[4]=v.x; A[5]=v.y; A[6]=v.z; A[7]=v.w;
    A[8] = Rw2[b + 8];
    v = *(const f4a*)(Rw1 + b);      B[0]=v.x; B[1]=v.y; B[2]=v.z; B[3]=v.w;
    v = *(const f4a*)(Rw1 + b + 4);  B[4]=v.x; B[5]=v.y; B[6]=v.z; B[7]=v.w;
    B[8] = Rw1[b + 8];
}

// Compute one element from 27 in-register inputs; NT-store gradients; return loss.
__device__ __forceinline__ float compute_store(
    const float R[9], const float A[9], const float B[9],
    float* __restrict__ o1, float* __restrict__ o2)
{
    // M = R_rel^T @ R_w2c2 ; M[i][k] = sum_j R[j][i]*A[j][k]
    float M[9];
    #pragma unroll
    for (int i = 0; i < 3; ++i)
        #pragma unroll
        for (int k = 0; k < 3; ++k)
            M[3 * i + k] = R[i]     * A[k]
                         + R[3 + i] * A[3 + k]
                         + R[6 + i] * A[6 + k];
    float tr = 0.0f;
    #pragma unroll
    for (int j = 0; j < 9; ++j) tr += M[j] * B[j];

    const float cosv = 0.5f * (tr - 1.0f);
    const float cosc = fminf(fmaxf(cosv, -CLAMP_THR), CLAMP_THR);
    const float g = (fabsf(cosv) < CLAMP_THR)
                      ? (-0.5f / sqrtf(1.0f - cosc * cosc))
                      : 0.0f;

    f4a s;
    s.x = g*M[0]; s.y = g*M[1]; s.z = g*M[2]; s.w = g*M[3];
    __builtin_nontemporal_store(s, (f4a*)o1);
    s.x = g*M[4]; s.y = g*M[5]; s.z = g*M[6]; s.w = g*M[7];
    __builtin_nontemporal_store(s, (f4a*)(o1 + 4));
    __builtin_nontemporal_store(g*M[8], o1 + 8);

    float D[9];
    #pragma unroll
    for (int i = 0; i < 3; ++i)
        #pragma unroll
        for (int k = 0; k < 3; ++k)
            D[3 * i + k] = g * (R[3 * i]     * B[k]
                              + R[3 * i + 1] * B[3 + k]
                              + R[3 * i + 2] * B[6 + k]);
    s.x = D[0]; s.y = D[1]; s.z = D[2]; s.w = D[3];
    __builtin_nontemporal_store(s, (f4a*)o2);
    s.x = D[4]; s.y = D[5]; s.z = D[6]; s.w = D[7];
    __builtin_nontemporal_store(s, (f4a*)(o2 + 4));
    __builtin_nontemporal_store(D[8], o2 + 8);

    return acosf(cosc);
}

// Persistent grid-stride waves with a 2-deep load pipeline + NT stores.
template<bool USE_WS>
__global__ __launch_bounds__(256) void geodesic_gs_kernel(
    const float* __restrict__ Rrel,   // [N,3,3]
    const float* __restrict__ Rw1,    // [N,3,3]  R_w2c1
    const float* __restrict__ Rw2,    // [N,3,3]  R_w2c2
    float* __restrict__ out,          // [1 + 9N + 9N]
    float* __restrict__ ws,           // per-block loss partials (USE_WS)
    int n)
{
    __shared__ float wsum[4];
    const int t = threadIdx.x;
    const int stride = gridDim.x * 256;
    int e = blockIdx.x * 256 + t;

    float* __restrict__ out1 = out + 1;
    float* __restrict__ out2 = out + 1 + (size_t)n * 9;

    float local_loss = 0.0f;
    float R[9], A[9], B[9];    // current element's inputs
    float Rn[9], An[9], Bn[9]; // next element's inputs (in flight)

    if (e < n) load27(Rrel, Rw2, Rw1, (size_t)e * 9, R, A, B);

    for (; e < n; e += stride) {
        const int en = e + stride;
        if (en < n)
            load27(Rrel, Rw2, Rw1, (size_t)en * 9, Rn, An, Bn);  // issue early

        const size_t b = (size_t)e * 9;
        local_loss += compute_store(R, A, B, out1 + b, out2 + b);

        #pragma unroll
        for (int j = 0; j < 9; ++j) { R[j] = Rn[j]; A[j] = An[j]; B[j] = Bn[j]; }
    }

    // ---- loss: wave shuffle reduce -> block partial (after all memory work) ----
    #pragma unroll
    for (int off = 32; off > 0; off >>= 1)
        local_loss += __shfl_down(local_loss, off, 64);
    if ((t & 63) == 0) wsum[t >> 6] = local_loss;
    __syncthreads();
    if (t == 0) {
        const float blocksum = wsum[0] + wsum[1] + wsum[2] + wsum[3];
        if (USE_WS) ws[blockIdx.x] = blocksum;
        else        atomicAdd(out, blocksum);
    }
}

__global__ __launch_bounds__(256) void reduce_loss_kernel(
    const float* __restrict__ ws, int nb, float* __restrict__ out)
{
    __shared__ float wsum[4];
    const int t = threadIdx.x;
    float s = 0.0f;
    for (int i = t; i < nb; i += 256) s += ws[i];
    #pragma unroll
    for (int off = 32; off > 0; off >>= 1)
        s += __shfl_down(s, off, 64);
    if ((t & 63) == 0) wsum[t >> 6] = s;
    __syncthreads();
    if (t == 0) out[0] = wsum[0] + wsum[1] + wsum[2] + wsum[3];
}

extern "C" void kernel_launch(void* const* d_in, const int* in_sizes, int n_in,
                              void* d_out, int out_size, void* d_ws, size_t ws_size,
                              hipStream_t stream) {
    const float* Rrel = (const float*)d_in[0];
    const float* Rw1  = (const float*)d_in[1];
    const float* Rw2  = (const float*)d_in[2];
    float* out = (float*)d_out;
    const int n = in_sizes[0] / 9;

    const int nChunks = (n + 255) / 256;
    const int grid = nChunks < 2048 ? nChunks : 2048;

    if (ws_size >= (size_t)grid * sizeof(float)) {
        geodesic_gs_kernel<true><<<grid, 256, 0, stream>>>(
            Rrel, Rw1, Rw2, out, (float*)d_ws, n);
        reduce_loss_kernel<<<1, 256, 0, stream>>>((const float*)d_ws, grid, out);
    } else {
        zero_loss_kernel<<<1, 64, 0, stream>>>(out);
        geodesic_gs_kernel<false><<<grid, 256, 0, stream>>>(
            Rrel, Rw1, Rw2, out, nullptr, n);
    }
}